// Round 16
// baseline (316.811 us; speedup 1.0000x reference)
//
#include <hip/hip_runtime.h>
#include <stdint.h>

// out[e,o] = sum_{i,h} A[e,i,h] * W[h,i,o],  A[e] = rbf[e] @ sph[e] @ m2[e]
// Fully fused, chunk c = (hw = c>>6, i = c&63), K=32 per chunk:
//   prolog: rs[e,i,k] = sum_s rbf[e,i,s] sphT[e,k,s]  -> LDS f16 (swizzled)
//   per chunk: A_c[e, 4h/thread] = v_dot2_f32_f16(rs-pairs, m2-kpairs) -> LDS dbuf
//              acc += A_c @ W_c  (mfma 16x16x32 F16; W via asm global_load, counted vmcnt)
// R16 vs R15: wave grid 1x8 -> 2e x 4o (wave tile 32e x 32o): af LDS traffic halves
// (16 KB vs 32 KB per block per chunk); bv 2 loads/wave, depth-2 prefetch, vmcnt(3)/(2).

#define EMB 128
#define INTERM 64
#define SPH_N 16
#define KMAX 8
#define OUTD 128
#define KDIM 8192
#define EB 64
#define NTHR 512
#define NCHUNK 256
#define ALD 36   // s_A row stride in ushorts (pad kills pow2 af-read conflicts)

typedef __attribute__((ext_vector_type(8))) __fp16 f16x8;
typedef __attribute__((ext_vector_type(2))) __fp16 f16x2;
typedef __attribute__((ext_vector_type(4))) float f32x4;
typedef __attribute__((ext_vector_type(4))) int i32x4;

#if defined(__has_builtin)
#if __has_builtin(__builtin_amdgcn_fdot2)
#define HAVE_FDOT2 1
#endif
#endif
#ifndef HAVE_FDOT2
#define HAVE_FDOT2 0
#endif

__device__ __forceinline__ unsigned short f32_to_f16u(float f) {
  union { f16x2 h; uint32_t u; } c; c.h = __builtin_amdgcn_cvt_pkrtz(f, f);
  return (unsigned short)(c.u & 0xffffu);
}
__device__ __forceinline__ uint32_t pk_f16(float lo, float hi) {
  union { f16x2 h; uint32_t u; } c; c.h = __builtin_amdgcn_cvt_pkrtz(lo, hi);
  return c.u;
}
__device__ __forceinline__ f16x8 as_h16(f32x4 v) {
  union { f32x4 f; f16x8 h; } u; u.f = v; return u.h;
}
__device__ __forceinline__ float dot2(f16x2 a, f16x2 b, float c) {
#if HAVE_FDOT2
  return __builtin_amdgcn_fdot2(a, b, c, false);
#else
  return c + (float)a[0] * (float)b[0] + (float)a[1] * (float)b[1];
#endif
}
// W load: 32-bit lane voffset + uniform SGPR base (asm => vmcnt-counted only)
__device__ __forceinline__ void gload_bv(f32x4& d, const unsigned short* sbase, uint32_t voff) {
  asm volatile("global_load_dwordx4 %0, %1, %2" : "=&v"(d) : "v"(voff), "s"(sbase));
}

__global__ void k_build_inv(const int* __restrict__ id_reduce,
                            const int* __restrict__ id_ragged,
                            int* __restrict__ inv, int nTrip, int E) {
  int t = blockIdx.x * blockDim.x + threadIdx.x;
  if (t >= nTrip) return;
  int e = id_reduce[t], k = id_ragged[t];
  if (e >= 0 && e < E && k >= 0 && k < KMAX) inv[e * KMAX + k] = t;
}

// W (h,i,o) f32 -> W2T[o][c = i*128 + h] f16
__global__ void k_w2t(const float* __restrict__ W, unsigned short* __restrict__ W2T) {
  int idx = blockIdx.x * blockDim.x + threadIdx.x;  // [0, 128*8192)
  int o = idx >> 13;
  int c = idx & (KDIM - 1);
  int h = c & 127, i = c >> 7;
  W2T[idx] = f32_to_f16u(W[(h * INTERM + i) * OUTD + o]);
}

// sphT[e][k][s] = sph[e][s][k]
__global__ void k_spht(const float* __restrict__ sph, float* __restrict__ sphT, int E) {
  int idx = blockIdx.x * blockDim.x + threadIdx.x;  // [0, E*128)
  int e = idx >> 7, r = idx & 127;
  if (e >= E) return;
  int k = r >> 4, s = r & 15;
  sphT[(size_t)e * 128 + k * 16 + s] = sph[(size_t)e * 128 + s * 8 + k];
}

__global__ __launch_bounds__(NTHR, 2) void k_fused(
    const float* __restrict__ rbf,   // [E][64][16]
    const float* __restrict__ sphT,  // [E][8][16]
    const float* __restrict__ m,     // [nTrip][128]
    const int* __restrict__ inv,     // [Epad][8]
    const unsigned short* __restrict__ W2T,  // [128][8192] f16
    float* __restrict__ out, int E)
{
  __shared__ unsigned short s_rs[EB * 64 * 8];  // 64 KB, rs[e][i][k] f16 xor-swizzled
  __shared__ unsigned short s_A[2][EB * ALD];   // 2 x 4.5 KB, A-chunk dbuf (padded rows)

  int tid = threadIdx.x;
  int e0 = blockIdx.x * EB;
  int eL = tid >> 3;          // 0..63 edge-local
  int kq = tid & 7;           // prolog: k ; main: h-quarter (4 h)
  int hq = kq;
  int eg = e0 + eL;
  bool ev = (eg < E);
  int esw8 = (eL & 7) << 3;   // rs swizzle (ushort units)

  // ---- prolog: rs[eL][i][kq] for all i (f32 math, f16 store)
  {
    f32x4 sp0 = 0.f, sp1 = 0.f, sp2 = 0.f, sp3 = 0.f;
    if (ev) {
      const f32x4* sp = (const f32x4*)(sphT + (size_t)eg * 128 + kq * 16);
      sp0 = sp[0]; sp1 = sp[1]; sp2 = sp[2]; sp3 = sp[3];
    }
    const f32x4* rb = (const f32x4*)(rbf + (size_t)eg * 1024);
#pragma unroll 4
    for (int i = 0; i < 64; ++i) {
      float v = 0.f;
      if (ev) {
        f32x4 q0 = rb[i * 4 + 0], q1 = rb[i * 4 + 1];
        f32x4 q2 = rb[i * 4 + 2], q3 = rb[i * 4 + 3];
        v = q0.x * sp0.x + q0.y * sp0.y + q0.z * sp0.z + q0.w * sp0.w
          + q1.x * sp1.x + q1.y * sp1.y + q1.z * sp1.z + q1.w * sp1.w
          + q2.x * sp2.x + q2.y * sp2.y + q2.z * sp2.z + q2.w * sp2.w
          + q3.x * sp3.x + q3.y * sp3.y + q3.z * sp3.z + q3.w * sp3.w;
      }
      s_rs[(eL << 9) + (((i << 3) ^ esw8) | kq)] = f32_to_f16u(v);
    }
  }

  // ---- GEMM roles: 8 waves = 2e x 4o; wave tile 32e x 32o
  int wid = tid >> 6, lane = tid & 63;
  int lr = lane & 15, lg = lane >> 4;
  int ew = wid >> 2, ow = wid & 3;
  int aidx0 = (ew * 32 + 0 * 16 + lr) * ALD + lg * 8;
  int aidx1 = (ew * 32 + 1 * 16 + lr) * ALD + lg * 8;
  uint32_t voff0 = (uint32_t)((((ow * 32 + 0 * 16 + lr) * KDIM) + lg * 8) * 2);
  uint32_t voff1 = voff0 + (uint32_t)(16 * KDIM * 2);

  // m2 packed in k-pairs: m2p[d][kp] = (m2[2kp][h_d], m2[2kp+1][h_d]), h_d = hw*32+hq*4+d
  f16x2 m2p[4][4];

#define LOAD_M2(HW)                                                              \
  {                                                                              \
    i32x4 iv0, iv1;                                                              \
    const int* ip_ = inv + (size_t)eg * 8;                                       \
    asm volatile("global_load_dwordx4 %0, %1, off" : "=&v"(iv0) : "v"(ip_));     \
    asm volatile("global_load_dwordx4 %0, %1, off" : "=&v"(iv1) : "v"(ip_ + 4)); \
    asm volatile("s_waitcnt vmcnt(0)" : "+v"(iv0), "+v"(iv1));                   \
    int tk_[8] = {iv0.x, iv0.y, iv0.z, iv0.w, iv1.x, iv1.y, iv1.z, iv1.w};       \
    f32x4 mm_[8];                                                                \
    _Pragma("unroll")                                                            \
    for (int k = 0; k < 8; ++k) {                                                \
      const float* mp_ = m + (size_t)(tk_[k] < 0 ? 0 : tk_[k]) * EMB             \
                         + (HW) * 32 + hq * 4;                                   \
      asm volatile("global_load_dwordx4 %0, %1, off" : "=&v"(mm_[k]) : "v"(mp_));\
    }                                                                            \
    asm volatile("s_waitcnt vmcnt(0)"                                            \
                 : "+v"(mm_[0]), "+v"(mm_[1]), "+v"(mm_[2]), "+v"(mm_[3]),       \
                   "+v"(mm_[4]), "+v"(mm_[5]), "+v"(mm_[6]), "+v"(mm_[7]));      \
    _Pragma("unroll")                                                            \
    for (int k = 0; k < 8; ++k)                                                  \
      if (tk_[k] < 0) mm_[k] = (f32x4){0.f, 0.f, 0.f, 0.f};                      \
    _Pragma("unroll")                                                            \
    for (int d = 0; d < 4; ++d) {                                                \
      _Pragma("unroll")                                                          \
      for (int kp = 0; kp < 4; ++kp)                                             \
        m2p[d][kp] = __builtin_amdgcn_cvt_pkrtz(mm_[2 * kp][d], mm_[2 * kp + 1][d]); \
    }                                                                            \
  }

#define PRODUCE(RR, B)                                                       \
  {                                                                          \
    union { uint4 u; f16x2 p[4]; } rsu; rsu.u = (RR);                        \
    float a0 = 0.f, a1 = 0.f, a2 = 0.f, a3 = 0.f;                            \
    _Pragma("unroll")                                                        \
    for (int kp = 0; kp < 4; ++kp) {                                         \
      a0 = dot2(rsu.p[kp], m2p[0][kp], a0);                                  \
      a1 = dot2(rsu.p[kp], m2p[1][kp], a1);                                  \
      a2 = dot2(rsu.p[kp], m2p[2][kp], a2);                                  \
      a3 = dot2(rsu.p[kp], m2p[3][kp], a3);                                  \
    }                                                                        \
    uint32_t p0 = pk_f16(a0, a1), p1 = pk_f16(a2, a3);                       \
    *(uint2*)&s_A[B][eL * ALD + hq * 4] = make_uint2(p0, p1);                \
  }

  f32x4 acc00 = {0.f, 0.f, 0.f, 0.f}, acc01 = acc00, acc10 = acc00, acc11 = acc00;
  f32x4 bvA0, bvA1, bvB0, bvB1;
  uint4 rsA, rsB;

  LOAD_M2(0)
  {
    uint4 rs0 = *(const uint4*)&s_rs[(eL << 9) + esw8];
    PRODUCE(rs0, 0)
  }
  rsA = *(const uint4*)&s_rs[(eL << 9) + ((1 << 3) ^ esw8)];
  gload_bv(bvA0, W2T + 0, voff0);   // chunk 0
  gload_bv(bvA1, W2T + 0, voff1);
  gload_bv(bvB0, W2T + 128, voff0); // chunk 1
  gload_bv(bvB1, W2T + 128, voff1);
  asm volatile("s_waitcnt lgkmcnt(0)" ::: "memory");
  __builtin_amdgcn_s_barrier();

#define BODY(C, CUR, BV0, BV1, BVN0, BVN1, RSP, RSF, W1S, W2S, PF, M2CHK, PROD)  \
  {                                                                              \
    const int c_ = (C);                                                          \
    f16x8 af0 = *(const f16x8*)&s_A[CUR][aidx0];                                 \
    f16x8 af1 = *(const f16x8*)&s_A[CUR][aidx1];                                 \
    RSF = *(const uint4*)&s_rs[(eL << 9) + ((((c_ + 2) & 63) << 3) ^ esw8)];     \
    if (M2CHK && (((c_ + 1) & 63) == 0)) LOAD_M2((c_ + 1) >> 6)                  \
    if (PROD) PRODUCE(RSP, (CUR) ^ 1)                                            \
    asm volatile(W1S : "+v"(BV0));                                               \
    {                                                                            \
      f16x8 bvv = as_h16(BV0);                                                   \
      acc00 = __builtin_amdgcn_mfma_f32_16x16x32_f16(af0, bvv, acc00, 0, 0, 0);  \
      acc10 = __builtin_amdgcn_mfma_f32_16x16x32_f16(af1, bvv, acc10, 0, 0, 0);  \
    }                                                                            \
    asm volatile(W2S : "+v"(BV1));                                               \
    {                                                                            \
      f16x8 bvv = as_h16(BV1);                                                   \
      acc01 = __builtin_amdgcn_mfma_f32_16x16x32_f16(af0, bvv, acc01, 0, 0, 0);  \
      acc11 = __builtin_amdgcn_mfma_f32_16x16x32_f16(af1, bvv, acc11, 0, 0, 0);  \
    }                                                                            \
    if (PF) {                                                                    \
      uint32_t wo_ = (uint32_t)((((c_ + 2) & 63) << 7) + (((c_ + 2) >> 6) << 5));\
      gload_bv(BVN0, W2T + wo_, voff0);                                          \
      gload_bv(BVN1, W2T + wo_, voff1);                                          \
    }                                                                            \
    asm volatile("s_waitcnt lgkmcnt(0)" ::: "memory");                           \
    __builtin_amdgcn_s_barrier();                                                \
  }

  for (int cc = 0; cc < NCHUNK - 2; cc += 2) {
    BODY(cc,     0, bvA0, bvA1, bvA0, bvA1, rsA, rsB,
         "s_waitcnt vmcnt(3)", "s_waitcnt vmcnt(2)", 1, 0, 1)
    BODY(cc + 1, 1, bvB0, bvB1, bvB0, bvB1, rsB, rsA,
         "s_waitcnt vmcnt(3)", "s_waitcnt vmcnt(2)", 1, 1, 1)
  }
  BODY(NCHUNK - 2, 0, bvA0, bvA1, bvA0, bvA1, rsA, rsB,
       "s_waitcnt vmcnt(3)", "s_waitcnt vmcnt(2)", 0, 0, 1)
  BODY(NCHUNK - 1, 1, bvB0, bvB1, bvB0, bvB1, rsB, rsA,
       "s_waitcnt vmcnt(1)", "s_waitcnt vmcnt(0)", 0, 0, 0)

  // ---- epilogue: C/D layout col = lane&15, row = (lane>>4)*4 + reg
  {
    int col0 = ow * 32 + lr, col1 = col0 + 16;
    int rbase = e0 + ew * 32 + lg * 4;
#pragma unroll
    for (int r = 0; r < 4; ++r) {
      int rA = rbase + r, rB = rbase + 16 + r;
      if (rA < E) {
        out[(size_t)rA * OUTD + col0] = acc00[r];
        out[(size_t)rA * OUTD + col1] = acc01[r];
      }
      if (rB < E) {
        out[(size_t)rB * OUTD + col0] = acc10[r];
        out[(size_t)rB * OUTD + col1] = acc11[r];
      }
    }
  }
}

extern "C" void kernel_launch(void* const* d_in, const int* in_sizes, int n_in,
                              void* d_out, int out_size, void* d_ws, size_t ws_size,
                              hipStream_t stream) {
  const float* rbf = (const float*)d_in[0];
  const float* sph = (const float*)d_in[1];
  const float* m   = (const float*)d_in[2];
  const float* W   = (const float*)d_in[3];
  const int* id_reduce = (const int*)d_in[4];
  const int* id_ragged = (const int*)d_in[5];
  float* out = (float*)d_out;

  int E = in_sizes[0] / (INTERM * SPH_N);   // 30000
  int nTrip = in_sizes[2] / EMB;            // 240000
  int nblk = (E + EB - 1) / EB;             // 469
  int Epad = nblk * EB;                     // 30016

  char* ws = (char*)d_ws;
  int* inv = (int*)ws;                                       // [0, 1 MB)
  unsigned short* W2T = (unsigned short*)(ws + (1u << 20));  // [1, 3 MB)
  float* sphT = (float*)(ws + (3u << 20));                   // [3, ~18.4 MB)

  (void)hipMemsetAsync(inv, 0xFF, (size_t)Epad * KMAX * sizeof(int), stream);
  k_build_inv<<<(nTrip + 255) / 256, 256, 0, stream>>>(id_reduce, id_ragged, inv, nTrip, E);
  k_w2t<<<(OUTD * KDIM) / 256, 256, 0, stream>>>(W, W2T);
  k_spht<<<(E * 128 + 255) / 256, 256, 0, stream>>>(sph, sphT, E);

  k_fused<<<nblk, NTHR, 0, stream>>>(rbf, sphT, m, inv, W2T, out, E);
}

// Round 17
// 207.226 us; speedup vs baseline: 1.5288x; 1.5288x over previous
//
#include <hip/hip_runtime.h>
#include <stdint.h>

// out[e,o] = sum_{i,h} A[e,i,h] * W[h,i,o],  A[e] = rbf[e] @ sph[e] @ m2[e]
// Fully fused. chunk c = (hw=c>>6, i=c&63), K=32/chunk; PERIOD = 2 chunks, ONE barrier.
//   prolog: rs[e,i,k] = sum_s rbf[e,i,s] sphT[e,k,s]  -> LDS f16 (swizzled)
//   per period p (chunks c=2p, c+1): 8 af ds_reads; produce chunks c+2,c+3 (fdot2)
//     into quad-buffer s_A[(p+1)&1][0/1]; 8 MFMA (f16 16x16x32); bv via asm
//     global_load with counted vmcnt(1) -- never drained across the barrier.
// R17 vs R15: barrier count halved (256 -> 128 periods); s_A quad-buffer XOR-swizzled.

#define EMB 128
#define INTERM 64
#define SPH_N 16
#define KMAX 8
#define OUTD 128
#define KDIM 8192
#define EB 64
#define NTHR 512
#define NCHUNK 256

typedef __attribute__((ext_vector_type(8))) __fp16 f16x8;
typedef __attribute__((ext_vector_type(2))) __fp16 f16x2;
typedef __attribute__((ext_vector_type(4))) float f32x4;
typedef __attribute__((ext_vector_type(4))) int i32x4;

#if defined(__has_builtin)
#if __has_builtin(__builtin_amdgcn_fdot2)
#define HAVE_FDOT2 1
#endif
#endif
#ifndef HAVE_FDOT2
#define HAVE_FDOT2 0
#endif

__device__ __forceinline__ unsigned short f32_to_f16u(float f) {
  union { f16x2 h; uint32_t u; } c; c.h = __builtin_amdgcn_cvt_pkrtz(f, f);
  return (unsigned short)(c.u & 0xffffu);
}
__device__ __forceinline__ uint32_t pk_f16(float lo, float hi) {
  union { f16x2 h; uint32_t u; } c; c.h = __builtin_amdgcn_cvt_pkrtz(lo, hi);
  return c.u;
}
__device__ __forceinline__ f16x8 as_h16(f32x4 v) {
  union { f32x4 f; f16x8 h; } u; u.f = v; return u.h;
}
__device__ __forceinline__ float dot2(f16x2 a, f16x2 b, float c) {
#if HAVE_FDOT2
  return __builtin_amdgcn_fdot2(a, b, c, false);
#else
  return c + (float)a[0] * (float)b[0] + (float)a[1] * (float)b[1];
#endif
}
// W load: 32-bit lane voffset + uniform SGPR base
__device__ __forceinline__ void gload_bv(f32x4& d, const unsigned short* sbase, uint32_t voff) {
  asm volatile("global_load_dwordx4 %0, %1, %2" : "=&v"(d) : "v"(voff), "s"(sbase));
}

__global__ void k_build_inv(const int* __restrict__ id_reduce,
                            const int* __restrict__ id_ragged,
                            int* __restrict__ inv, int nTrip, int E) {
  int t = blockIdx.x * blockDim.x + threadIdx.x;
  if (t >= nTrip) return;
  int e = id_reduce[t], k = id_ragged[t];
  if (e >= 0 && e < E && k >= 0 && k < KMAX) inv[e * KMAX + k] = t;
}

// W (h,i,o) f32 -> W2T[o][c = i*128 + h] f16
__global__ void k_w2t(const float* __restrict__ W, unsigned short* __restrict__ W2T) {
  int idx = blockIdx.x * blockDim.x + threadIdx.x;  // [0, 128*8192)
  int o = idx >> 13;
  int c = idx & (KDIM - 1);
  int h = c & 127, i = c >> 7;
  W2T[idx] = f32_to_f16u(W[(h * INTERM + i) * OUTD + o]);
}

// sphT[e][k][s] = sph[e][s][k]
__global__ void k_spht(const float* __restrict__ sph, float* __restrict__ sphT, int E) {
  int idx = blockIdx.x * blockDim.x + threadIdx.x;  // [0, E*128)
  int e = idx >> 7, r = idx & 127;
  if (e >= E) return;
  int k = r >> 4, s = r & 15;
  sphT[(size_t)e * 128 + k * 16 + s] = sph[(size_t)e * 128 + s * 8 + k];
}

__global__ __launch_bounds__(NTHR, 2) void k_fused(
    const float* __restrict__ rbf,   // [E][64][16]
    const float* __restrict__ sphT,  // [E][8][16]
    const float* __restrict__ m,     // [nTrip][128]
    const int* __restrict__ inv,     // [Epad][8]
    const unsigned short* __restrict__ W2T,  // [128][8192] f16
    float* __restrict__ out, int E)
{
  __shared__ unsigned short s_rs[EB * 64 * 8];    // 64 KB, rs[e][i][k] f16 xor-swizzled
  __shared__ unsigned short s_A[2][2][EB * 32];   // 16 KB quad-buffer, XOR-swizzled

  int tid = threadIdx.x;
  int e0 = blockIdx.x * EB;
  int eL = tid >> 3;          // 0..63 edge-local
  int kq = tid & 7;           // prolog: k ; main: h-quarter (4 h)
  int hq = kq;
  int eg = e0 + eL;
  bool ev = (eg < E);
  int esw8 = (eL & 7) << 3;   // rs swizzle (ushort units)
  int asw  = (eL & 3) << 3;   // s_A write swizzle

  // ---- prolog: rs[eL][i][kq] for all i (f32 math, f16 store)
  {
    f32x4 sp0 = 0.f, sp1 = 0.f, sp2 = 0.f, sp3 = 0.f;
    if (ev) {
      const f32x4* sp = (const f32x4*)(sphT + (size_t)eg * 128 + kq * 16);
      sp0 = sp[0]; sp1 = sp[1]; sp2 = sp[2]; sp3 = sp[3];
    }
    const f32x4* rb = (const f32x4*)(rbf + (size_t)eg * 1024);
#pragma unroll 4
    for (int i = 0; i < 64; ++i) {
      float v = 0.f;
      if (ev) {
        f32x4 q0 = rb[i * 4 + 0], q1 = rb[i * 4 + 1];
        f32x4 q2 = rb[i * 4 + 2], q3 = rb[i * 4 + 3];
        v = q0.x * sp0.x + q0.y * sp0.y + q0.z * sp0.z + q0.w * sp0.w
          + q1.x * sp1.x + q1.y * sp1.y + q1.z * sp1.z + q1.w * sp1.w
          + q2.x * sp2.x + q2.y * sp2.y + q2.z * sp2.z + q2.w * sp2.w
          + q3.x * sp3.x + q3.y * sp3.y + q3.z * sp3.z + q3.w * sp3.w;
      }
      s_rs[(eL << 9) + (((i << 3) ^ esw8) | kq)] = f32_to_f16u(v);
    }
  }

  // ---- GEMM roles: 8 waves, 1x8 grid; wave tile 64e x 16o (no bv dup)
  int wid = tid >> 6, lane = tid & 63;
  int lr = lane & 15, lg = lane >> 4;
  int aidx0 = ((0 * 16 + lr) << 5) + ((lg << 3) ^ ((lr & 3) << 3));
  int aidx1 = ((1 * 16 + lr) << 5) + ((lg << 3) ^ ((lr & 3) << 3));
  int aidx2 = ((2 * 16 + lr) << 5) + ((lg << 3) ^ ((lr & 3) << 3));
  int aidx3 = ((3 * 16 + lr) << 5) + ((lg << 3) ^ ((lr & 3) << 3));
  uint32_t voff = (uint32_t)((((wid * 16 + lr) * KDIM) + lg * 8) * 2);

  // m2 packed in k-pairs: m2p[d][kp] = (m2[2kp][h_d], m2[2kp+1][h_d]), h_d = hw*32+hq*4+d
  f16x2 m2p[4][4];

#define LOAD_M2(HW)                                                              \
  {                                                                              \
    i32x4 iv0, iv1;                                                              \
    const int* ip_ = inv + (size_t)eg * 8;                                       \
    asm volatile("global_load_dwordx4 %0, %1, off" : "=&v"(iv0) : "v"(ip_));     \
    asm volatile("global_load_dwordx4 %0, %1, off" : "=&v"(iv1) : "v"(ip_ + 4)); \
    asm volatile("s_waitcnt vmcnt(0)" : "+v"(iv0), "+v"(iv1));                   \
    int tk_[8] = {iv0.x, iv0.y, iv0.z, iv0.w, iv1.x, iv1.y, iv1.z, iv1.w};       \
    f32x4 mm_[8];                                                                \
    _Pragma("unroll")                                                            \
    for (int k = 0; k < 8; ++k) {                                                \
      const float* mp_ = m + (size_t)(tk_[k] < 0 ? 0 : tk_[k]) * EMB             \
                         + (HW) * 32 + hq * 4;                                   \
      asm volatile("global_load_dwordx4 %0, %1, off" : "=&v"(mm_[k]) : "v"(mp_));\
    }                                                                            \
    asm volatile("s_waitcnt vmcnt(0)"                                            \
                 : "+v"(mm_[0]), "+v"(mm_[1]), "+v"(mm_[2]), "+v"(mm_[3]),       \
                   "+v"(mm_[4]), "+v"(mm_[5]), "+v"(mm_[6]), "+v"(mm_[7]));      \
    _Pragma("unroll")                                                            \
    for (int k = 0; k < 8; ++k)                                                  \
      if (tk_[k] < 0) mm_[k] = (f32x4){0.f, 0.f, 0.f, 0.f};                      \
    _Pragma("unroll")                                                            \
    for (int d = 0; d < 4; ++d) {                                                \
      _Pragma("unroll")                                                          \
      for (int kp = 0; kp < 4; ++kp)                                             \
        m2p[d][kp] = __builtin_amdgcn_cvt_pkrtz(mm_[2 * kp][d], mm_[2 * kp + 1][d]); \
    }                                                                            \
  }

#define PRODUCE(RR, PAR, SL)                                                 \
  {                                                                          \
    union { uint4 u; f16x2 p[4]; } rsu; rsu.u = (RR);                        \
    float a0 = 0.f, a1 = 0.f, a2 = 0.f, a3 = 0.f;                            \
    _Pragma("unroll")                                                        \
    for (int kp = 0; kp < 4; ++kp) {                                         \
      a0 = dot2(rsu.p[kp], m2p[0][kp], a0);                                  \
      a1 = dot2(rsu.p[kp], m2p[1][kp], a1);                                  \
      a2 = dot2(rsu.p[kp], m2p[2][kp], a2);                                  \
      a3 = dot2(rsu.p[kp], m2p[3][kp], a3);                                  \
    }                                                                        \
    uint32_t p0 = pk_f16(a0, a1), p1 = pk_f16(a2, a3);                       \
    *(uint2*)&s_A[PAR][SL][(eL << 5) + ((hq << 2) ^ asw)] =                  \
        make_uint2(p0, p1);                                                  \
  }

  f32x4 acc0 = {0.f, 0.f, 0.f, 0.f}, acc1 = acc0, acc2 = acc0, acc3 = acc0;
  f32x4 bvA, bvB;
  uint4 rsA0, rsA1, rsB0, rsB1;

  LOAD_M2(0)
  {
    uint4 rs0 = *(const uint4*)&s_rs[(eL << 9) + esw8];
    uint4 rs1 = *(const uint4*)&s_rs[(eL << 9) + ((1 << 3) ^ esw8)];
    PRODUCE(rs0, 0, 0)
    PRODUCE(rs1, 0, 1)
  }
  rsA0 = *(const uint4*)&s_rs[(eL << 9) + ((2 << 3) ^ esw8)];
  rsA1 = *(const uint4*)&s_rs[(eL << 9) + ((3 << 3) ^ esw8)];
  gload_bv(bvA, W2T + 0, voff);     // chunk 0
  gload_bv(bvB, W2T + 128, voff);   // chunk 1
  asm volatile("s_waitcnt lgkmcnt(0)" ::: "memory");
  __builtin_amdgcn_s_barrier();

#define PERIOD(P, PAR, RSP0, RSP1, RSF0, RSF1, M2CHK, PROD, PF, W1S, W2S)        \
  {                                                                              \
    const int c_ = 2 * (P);                                                      \
    f16x8 a00 = *(const f16x8*)&s_A[PAR][0][aidx0];                              \
    f16x8 a01 = *(const f16x8*)&s_A[PAR][0][aidx1];                              \
    f16x8 a02 = *(const f16x8*)&s_A[PAR][0][aidx2];                              \
    f16x8 a03 = *(const f16x8*)&s_A[PAR][0][aidx3];                              \
    f16x8 a10 = *(const f16x8*)&s_A[PAR][1][aidx0];                              \
    f16x8 a11 = *(const f16x8*)&s_A[PAR][1][aidx1];                              \
    f16x8 a12 = *(const f16x8*)&s_A[PAR][1][aidx2];                              \
    f16x8 a13 = *(const f16x8*)&s_A[PAR][1][aidx3];                              \
    if (PF) {                                                                    \
      RSF0 = *(const uint4*)&s_rs[(eL << 9) + ((((c_ + 4) & 63) << 3) ^ esw8)];  \
      RSF1 = *(const uint4*)&s_rs[(eL << 9) + ((((c_ + 5) & 63) << 3) ^ esw8)];  \
    }                                                                            \
    if (M2CHK && (((c_ + 2) & 63) == 0)) LOAD_M2((c_ + 2) >> 6)                  \
    if (PROD) { PRODUCE(RSP0, (PAR) ^ 1, 0) PRODUCE(RSP1, (PAR) ^ 1, 1) }        \
    asm volatile(W1S : "+v"(bvA));                                               \
    {                                                                            \
      f16x8 bvv = as_h16(bvA);                                                   \
      acc0 = __builtin_amdgcn_mfma_f32_16x16x32_f16(a00, bvv, acc0, 0, 0, 0);    \
      acc1 = __builtin_amdgcn_mfma_f32_16x16x32_f16(a01, bvv, acc1, 0, 0, 0);    \
      acc2 = __builtin_amdgcn_mfma_f32_16x16x32_f16(a02, bvv, acc2, 0, 0, 0);    \
      acc3 = __builtin_amdgcn_mfma_f32_16x16x32_f16(a03, bvv, acc3, 0, 0, 0);    \
    }                                                                            \
    if (PF) {                                                                    \
      uint32_t wo_ = (uint32_t)((((c_ + 2) & 63) << 7) + (((c_ + 2) >> 6) << 5));\
      gload_bv(bvA, W2T + wo_, voff);                                            \
    }                                                                            \
    asm volatile(W2S : "+v"(bvB));                                               \
    {                                                                            \
      f16x8 bvv = as_h16(bvB);                                                   \
      acc0 = __builtin_amdgcn_mfma_f32_16x16x32_f16(a10, bvv, acc0, 0, 0, 0);    \
      acc1 = __builtin_amdgcn_mfma_f32_16x16x32_f16(a11, bvv, acc1, 0, 0, 0);    \
      acc2 = __builtin_amdgcn_mfma_f32_16x16x32_f16(a12, bvv, acc2, 0, 0, 0);    \
      acc3 = __builtin_amdgcn_mfma_f32_16x16x32_f16(a13, bvv, acc3, 0, 0, 0);    \
    }                                                                            \
    if (PF) {                                                                    \
      uint32_t wo_ = (uint32_t)((((c_ + 3) & 63) << 7) + (((c_ + 3) >> 6) << 5));\
      gload_bv(bvB, W2T + wo_, voff);                                            \
    }                                                                            \
    asm volatile("s_waitcnt lgkmcnt(0)" ::: "memory");                           \
    __builtin_amdgcn_s_barrier();                                                \
  }

  for (int p = 0; p < 126; p += 2) {
    PERIOD(p,     0, rsA0, rsA1, rsB0, rsB1, 1, 1, 1,
           "s_waitcnt vmcnt(1)", "s_waitcnt vmcnt(1)")
    PERIOD(p + 1, 1, rsB0, rsB1, rsA0, rsA1, 1, 1, 1,
           "s_waitcnt vmcnt(1)", "s_waitcnt vmcnt(1)")
  }
  PERIOD(126, 0, rsA0, rsA1, rsB0, rsB1, 0, 1, 1,
         "s_waitcnt vmcnt(1)", "s_waitcnt vmcnt(1)")
  PERIOD(127, 1, rsB0, rsB1, rsA0, rsA1, 0, 0, 0,
         "s_waitcnt vmcnt(1)", "s_waitcnt vmcnt(0)")

  // ---- epilogue: C/D layout col = lane&15, row = (lane>>4)*4 + reg
  {
    int col = wid * 16 + lr;
#pragma unroll
    for (int r = 0; r < 4; ++r) {
      int rb_ = e0 + lg * 4 + r;
      if (rb_ + 0 < E)  out[(size_t)(rb_ + 0)  * OUTD + col] = acc0[r];
      if (rb_ + 16 < E) out[(size_t)(rb_ + 16) * OUTD + col] = acc1[r];
      if (rb_ + 32 < E) out[(size_t)(rb_ + 32) * OUTD + col] = acc2[r];
      if (rb_ + 48 < E) out[(size_t)(rb_ + 48) * OUTD + col] = acc3[r];
    }
  }
}

extern "C" void kernel_launch(void* const* d_in, const int* in_sizes, int n_in,
                              void* d_out, int out_size, void* d_ws, size_t ws_size,
                              hipStream_t stream) {
  const float* rbf = (const float*)d_in[0];
  const float* sph = (const float*)d_in[1];
  const float* m   = (const float*)d_in[2];
  const float* W   = (const float*)d_in[3];
  const int* id_reduce = (const int*)d_in[4];
  const int* id_ragged = (const int*)d_in[5];
  float* out = (float*)d_out;

  int E = in_sizes[0] / (INTERM * SPH_N);   // 30000
  int nTrip = in_sizes[2] / EMB;            // 240000
  int nblk = (E + EB - 1) / EB;             // 469
  int Epad = nblk * EB;                     // 30016

  char* ws = (char*)d_ws;
  int* inv = (int*)ws;                                       // [0, 1 MB)
  unsigned short* W2T = (unsigned short*)(ws + (1u << 20));  // [1, 3 MB)
  float* sphT = (float*)(ws + (3u << 20));                   // [3, ~18.4 MB)

  (void)hipMemsetAsync(inv, 0xFF, (size_t)Epad * KMAX * sizeof(int), stream);
  k_build_inv<<<(nTrip + 255) / 256, 256, 0, stream>>>(id_reduce, id_ragged, inv, nTrip, E);
  k_w2t<<<(OUTD * KDIM) / 256, 256, 0, stream>>>(W, W2T);
  k_spht<<<(E * 128 + 255) / 256, 256, 0, stream>>>(sph, sphT, E);

  k_fused<<<nblk, NTHR, 0, stream>>>(rbf, sphT, m, inv, W2T, out, E);
}